// Round 4
// baseline (361.147 us; speedup 1.0000x reference)
//
#include <hip/hip_runtime.h>

#define DD 2048   // D = 2*hidden
#define BB 16     // batch
#define SS 2048   // seq
#define DPB 2     // d-columns per block in linear kernel

// native vector type: accepted by __builtin_nontemporal_load (HIP's float4
// class type is not)
typedef float f4 __attribute__((ext_vector_type(4)));

// Kernel 1: altered[b, d] = bias[d] + sum_k state[b,k] * W[d,k]
// One block per DPB output columns. W rows streamed once (nontemporal);
// state (128 KiB) stays L2-resident, read once per block (DPB d's amortize).
// Reduction: log-merge (16 accs -> 1 per lane in 15 shuffles + 2 group
// shuffles) instead of 16 full butterflies (96 shuffles).
__global__ __launch_bounds__(256) void linear_kernel(
    const float* __restrict__ state,   // [B, D]
    const float* __restrict__ W,       // [D, D] row-major, W[d, k]
    const float* __restrict__ bias,    // [D]
    float* __restrict__ altered)       // [B, D]
{
    const int d0   = blockIdx.x * DPB;
    const int tid  = threadIdx.x;
    const int lane = tid & 63;
    const int wave = tid >> 6;

    const f4* S4 = (const f4*)state;   // B * 512 f4

    float acc[DPB][BB];
#pragma unroll
    for (int p = 0; p < DPB; ++p)
#pragma unroll
        for (int b = 0; b < BB; ++b) acc[p][b] = 0.f;

#pragma unroll
    for (int it = 0; it < 2; ++it) {
        const int k4 = tid + it * 256;           // 0..511
        f4 w[DPB];
#pragma unroll
        for (int p = 0; p < DPB; ++p)
            w[p] = __builtin_nontemporal_load(
                       &((const f4*)(W + (size_t)(d0 + p) * DD))[k4]);
#pragma unroll
        for (int b = 0; b < BB; ++b) {
            const f4 s = S4[b * 512 + k4];
#pragma unroll
            for (int p = 0; p < DPB; ++p)
                acc[p][b] += w[p].x * s.x + w[p].y * s.y
                           + w[p].z * s.z + w[p].w * s.w;
        }
    }

    __shared__ float red[4][DPB][BB];
#pragma unroll
    for (int p = 0; p < DPB; ++p) {
        float v[BB];
#pragma unroll
        for (int b = 0; b < BB; ++b) v[b] = acc[p][b];

        // merge stages: 16 -> 8 -> 4 -> 2 -> 1 accs/lane (offsets 1,2,4,8)
#pragma unroll
        for (int st = 0; st < 4; ++st) {
            const int off = 1 << st;
            const int c2  = BB >> (st + 1);      // 8,4,2,1
            const bool hi = (lane & off) != 0;
#pragma unroll
            for (int i = 0; i < 8; ++i) {
                if (i < c2) {
                    const float send = hi ? v[i] : v[i + c2];
                    const float keep = hi ? v[i + c2] : v[i];
                    v[i] = keep + __shfl_xor(send, off, 64);
                }
            }
        }
        // lane L now holds b = bitrev4(L&15), summed over its 16-lane group
        float t = v[0];
        t += __shfl_xor(t, 16, 64);
        t += __shfl_xor(t, 32, 64);
        if (lane < BB) {
            const int b = ((lane & 1) << 3) | ((lane & 2) << 1)
                        | ((lane & 4) >> 1) | ((lane & 8) >> 3);
            red[wave][p][b] = t;
        }
    }
    __syncthreads();

    if (tid < BB * DPB) {                        // 32 threads store
        const int p = tid >> 4;
        const int b = tid & 15;
        const int d = d0 + p;
        altered[b * DD + d] = red[0][p][b] + red[1][p][b]
                            + red[2][p][b] + red[3][p][b] + bias[d];
    }
}

// Kernel 2: out[b, s] = sum_d altered[b,d] * enc[s,b,d]
// 8192 persistent waves; wave wv handles wid = wv + it*8192, it=0..3.
// b = wv & 15 constant per wave -> altered[b,:] loaded ONCE into 32 VGPRs.
// Hot loop is pure NT dwordx4 loads + packed FMAs into 4 independent f4
// accumulators; all cross-lane reduction deferred to after the loop.
__global__ __launch_bounds__(256) void attend_kernel(
    const float* __restrict__ enc,      // [S, B, D]
    const float* __restrict__ altered,  // [B, D]
    float* __restrict__ out)            // [B, S]
{
    const int lane = threadIdx.x & 63;
    const int wv   = blockIdx.x * 4 + (threadIdx.x >> 6);  // 0..8191
    const int b    = wv & (BB - 1);

    const f4* A4 = (const f4*)altered + (size_t)b * 512;
    f4 a[8];
#pragma unroll
    for (int j = 0; j < 8; ++j) a[j] = A4[j * 64 + lane];

    const f4* E4 = (const f4*)enc;
    f4 acc[4];
#pragma unroll
    for (int it = 0; it < 4; ++it) acc[it] = (f4)0.f;

#pragma unroll
    for (int it = 0; it < 4; ++it) {
        const size_t base = (size_t)(wv + it * 8192) * 512;
        f4 e[8];
#pragma unroll
        for (int j = 0; j < 8; ++j)
            e[j] = __builtin_nontemporal_load(&E4[base + j * 64 + lane]);
#pragma unroll
        for (int j = 0; j < 8; ++j)
            acc[it] += e[j] * a[j];
    }

#pragma unroll
    for (int it = 0; it < 4; ++it) {
        float t = acc[it].x + acc[it].y + acc[it].z + acc[it].w;
#pragma unroll
        for (int off = 32; off > 0; off >>= 1)
            t += __shfl_xor(t, off, 64);
        if (lane == 0) out[b * SS + (wv >> 4) + it * 512] = t;
    }
}

extern "C" void kernel_launch(void* const* d_in, const int* in_sizes, int n_in,
                              void* d_out, int out_size, void* d_ws, size_t ws_size,
                              hipStream_t stream) {
    const float* enc   = (const float*)d_in[0];  // [S, B, D]
    const float* state = (const float*)d_in[1];  // [B, D]
    const float* W     = (const float*)d_in[2];  // [D, D]
    const float* bias  = (const float*)d_in[3];  // [D]
    float*       out   = (float*)d_out;          // [B, S]

    float* altered = (float*)d_ws;               // [B, D] = 128 KiB scratch

    linear_kernel<<<DD / DPB, 256, 0, stream>>>(state, W, bias, altered);

    attend_kernel<<<2048, 256, 0, stream>>>(enc, altered, out);
}